// Round 7
// baseline (964.588 us; speedup 1.0000x reference)
//
#include <hip/hip_runtime.h>
#include <math.h>

// ---------------------------------------------------------------------------
// HGT on MI355X — round 8 (resubmit; r8 bench was an infra failure).
//  * Base: r6 (834 µs; BRES qkv GEMM, NT out/x hints). r7's occupancy diet
//    regressed (+66 µs = the extra L3 traffic it introduced) and is reverted.
//  * Single change: attention + out-proj FUSED into one kernel per layer.
//    Block = 128 dst nodes: phase 1 computes attention (4-edge-parallel,
//    32 nodes/wave) -> gelu -> 32KB LDS (XOR-swizzled, conflict-free);
//    phase 2 out-proj MFMA reads B-fragments from LDS; skip-mix epilogue.
//    Kills the agg round-trip (152 MB/iter) + 2 dispatch drains.
// ---------------------------------------------------------------------------

#define HID 128
#define OLD 384   // d_out row stride = 3*HID

typedef __attribute__((ext_vector_type(8))) short short8;
typedef __attribute__((ext_vector_type(4))) float f32x4;

__device__ __forceinline__ unsigned short f2b(float f) {
    unsigned u = __float_as_uint(f);
    u += 0x7fffu + ((u >> 16) & 1u);          // RNE
    return (unsigned short)(u >> 16);
}
__device__ __forceinline__ unsigned pk2(float a, float b) {
    return (unsigned)f2b(a) | ((unsigned)f2b(b) << 16);
}
__device__ __forceinline__ float blo(unsigned u) { return __uint_as_float(u << 16); }
__device__ __forceinline__ float bhi(unsigned u) { return __uint_as_float(u & 0xffff0000u); }
__device__ __forceinline__ float gelu_f(float x) {
    return 0.5f * x * (1.0f + erff(x * 0.70710678118654752f));
}

// non-temporal helpers (evict-first hint; keeps L3 for the hot working set)
__device__ __forceinline__ void nt_st_f32x4(float* p, float a, float b,
                                            float c, float d) {
    f32x4 v = {a, b, c, d};
    __builtin_nontemporal_store(v, (f32x4*)p);
}
__device__ __forceinline__ f32x4 nt_ld_f32x4(const float* p) {
    return __builtin_nontemporal_load((const f32x4*)p);
}

// ---------------------------------------------------------------------------
// MFMA GEMM body (transposed operands): D = W^T-as-A x activations-as-B.
// Wp frag-packed per 128x128 block: [mt(8)][kt(4)][lane(64)][j(8)].
// Merged over two node types: first yb0 blocks = slot 0, rest = slot 1.
// ct loop (col-blocks) runs inside the block; BRES=1 keeps B-fragments
// register-resident across the ct loop.
// EPI 0: bf16 -> Cb[node*ldcb + ct*128 + oc]                       (qkv)
// EPI 1: relu; fp32 -> Cf[node*ldcf+oc], bf16 -> Cb[node*128+oc]   (in-proj)
// ---------------------------------------------------------------------------
template <int AFP32>
__device__ __forceinline__ void load_bfrag(short8 (&d)[4], const void* Aptr,
                                           int lda, int node, int kq)
{
    if (AFP32) {
        const float* ar = (const float*)Aptr + (size_t)node * lda;
#pragma unroll
        for (int kt = 0; kt < 4; ++kt) {
            f32x4 v0 = nt_ld_f32x4(ar + kt * 32 + kq * 8);
            f32x4 v1 = nt_ld_f32x4(ar + kt * 32 + kq * 8 + 4);
            short8 t;
            t[0] = (short)f2b(v0[0]); t[1] = (short)f2b(v0[1]);
            t[2] = (short)f2b(v0[2]); t[3] = (short)f2b(v0[3]);
            t[4] = (short)f2b(v1[0]); t[5] = (short)f2b(v1[1]);
            t[6] = (short)f2b(v1[2]); t[7] = (short)f2b(v1[3]);
            d[kt] = t;
        }
    } else {
        const unsigned short* ar = (const unsigned short*)Aptr + (size_t)node * lda;
#pragma unroll
        for (int kt = 0; kt < 4; ++kt)
            d[kt] = *(const short8*)(ar + kt * 32 + kq * 8);
    }
}

template <int AFP32, int EPI, int BRES>
__device__ __forceinline__ void gemm_body(
    int yb,
    const void* __restrict__ A0, const void* __restrict__ A1, int lda,
    const unsigned short* __restrict__ Wp, const float* __restrict__ biasP,
    int wblk0, int wblk1, int nct0, int nct1,
    unsigned short* __restrict__ Cb0, unsigned short* __restrict__ Cb1,
    int ldcb0, int ldcb1,
    float* __restrict__ Cf0, float* __restrict__ Cf1, int ldcf,
    int M0, int M1, int yb0)
{
    const int tid  = threadIdx.x;
    const int wid  = tid >> 6;
    const int lane = tid & 63;
    const int ow = (wid >> 1) * 64;     // outch offset in 128-block
    const int nw = (wid & 1) * 64;      // node offset in 128-tile
    const int lm = lane & 15;
    const int kq = lane >> 4;

    const int t  = (yb >= yb0) ? 1 : 0;
    const int r0 = (t ? (yb - yb0) : yb) * 128;
    const int M    = t ? M1 : M0;
    const int nct  = t ? nct1 : nct0;
    const int wblk = t ? wblk1 : wblk0;
    const void* Aptr = t ? A1 : A0;
    unsigned short* Cb = t ? Cb1 : Cb0;
    const int ldcb = t ? ldcb1 : ldcb0;
    float* Cf = t ? Cf1 : Cf0;

    // ---- B fragments (activations), optionally resident across ct loop ----
    short8 bres[4][4];
    if (BRES) {
#pragma unroll
        for (int ni = 0; ni < 4; ++ni) {
            int node = r0 + nw + ni * 16 + lm;
            node = (node < M) ? node : (M - 1);
            load_bfrag<AFP32>(bres[ni], Aptr, lda, node, kq);
        }
    }

    for (int ct = 0; ct < nct; ++ct) {
        const unsigned short* wbase = Wp + (size_t)(wblk + ct) * 16384;
        short8 wf[4][4];
#pragma unroll
        for (int mi = 0; mi < 4; ++mi) {
            const int mt = (ow >> 4) + mi;
#pragma unroll
            for (int kt = 0; kt < 4; ++kt)
                wf[mi][kt] = *(const short8*)(wbase + (((mt * 4 + kt) * 64 + lane) << 3));
        }

        f32x4 acc[4][4];    // [ni][mi]
#pragma unroll
        for (int ni = 0; ni < 4; ++ni)
#pragma unroll
            for (int mi = 0; mi < 4; ++mi)
                acc[ni][mi] = (f32x4){0.f, 0.f, 0.f, 0.f};

#pragma unroll
        for (int ni = 0; ni < 4; ++ni) {
            if (BRES) {
#pragma unroll
                for (int kt = 0; kt < 4; ++kt)
#pragma unroll
                    for (int mi = 0; mi < 4; ++mi)
                        acc[ni][mi] = __builtin_amdgcn_mfma_f32_16x16x32_bf16(
                            wf[mi][kt], bres[ni][kt], acc[ni][mi], 0, 0, 0);
            } else {
                int node = r0 + nw + ni * 16 + lm;
                node = (node < M) ? node : (M - 1);
                short8 bl[4];
                load_bfrag<AFP32>(bl, Aptr, lda, node, kq);
#pragma unroll
                for (int kt = 0; kt < 4; ++kt)
#pragma unroll
                    for (int mi = 0; mi < 4; ++mi)
                        acc[ni][mi] = __builtin_amdgcn_mfma_f32_16x16x32_bf16(
                            wf[mi][kt], bl[kt], acc[ni][mi], 0, 0, 0);
            }
        }

        // ---- epilogue: lane owns 4 consecutive outch per (ni,mi) ----
        float4 b4[4];
#pragma unroll
        for (int mi = 0; mi < 4; ++mi)
            b4[mi] = *(const float4*)(biasP + (wblk + ct) * 128 + ow + mi * 16 + kq * 4);

#pragma unroll
        for (int ni = 0; ni < 4; ++ni) {
            const int node = r0 + nw + ni * 16 + lm;
            if (node >= M) continue;
#pragma unroll
            for (int mi = 0; mi < 4; ++mi) {
                const int oc = ow + mi * 16 + kq * 4;
                float v0 = acc[ni][mi][0] + b4[mi].x;
                float v1 = acc[ni][mi][1] + b4[mi].y;
                float v2 = acc[ni][mi][2] + b4[mi].z;
                float v3 = acc[ni][mi][3] + b4[mi].w;
                if (EPI == 1) {
                    v0 = fmaxf(v0, 0.f); v1 = fmaxf(v1, 0.f);
                    v2 = fmaxf(v2, 0.f); v3 = fmaxf(v3, 0.f);
                }
                if (EPI != 0) {
                    nt_st_f32x4(Cf + (size_t)node * ldcf + oc, v0, v1, v2, v3);
                    *(uint2*)(Cb + (size_t)node * 128 + oc) =
                        make_uint2(pk2(v0, v1), pk2(v2, v3));
                } else {
                    *(uint2*)(Cb + (size_t)node * ldcb + ct * 128 + oc) =
                        make_uint2(pk2(v0, v1), pk2(v2, v3));
                }
            }
        }
    }
}

template <int AFP32, int EPI, int BRES>
__global__ __launch_bounds__(256) void mfma_gemm(
    const void* __restrict__ A0, const void* __restrict__ A1, int lda,
    const unsigned short* __restrict__ Wp, const float* __restrict__ biasP,
    int wblk0, int wblk1, int nct0, int nct1,
    unsigned short* __restrict__ Cb0, unsigned short* __restrict__ Cb1,
    int ldcb0, int ldcb1,
    float* __restrict__ Cf0, float* __restrict__ Cf1, int ldcf,
    int M0, int M1, int yb0)
{
    gemm_body<AFP32, EPI, BRES>(blockIdx.x, A0, A1, lda, Wp, biasP,
        wblk0, wblk1, nct0, nct1, Cb0, Cb1, ldcb0, ldcb1,
        Cf0, Cf1, ldcf, M0, M1, yb0);
}

// ---------------------------------------------------------------------------
// Attention inner loop, 4 edges in parallel per wave (unchanged from r5/r6).
// Lane = g*16 + u: group g (0..3) owns edge p0 + it*4 + g; lane u (0..15)
// owns channels u*8 .. u*8+7 (head = u>>2). Per-head dot reduced over the
// 4-lane quarter cluster (xor 1,2); per-group online-softmax states merged
// at the end (max/rescale/sum butterfly over xor 16,32). Finite sentinels
// make empty/masked edges contribute exactly 0.
// ---------------------------------------------------------------------------
__device__ __forceinline__ void attn_loop4(
    const unsigned short* __restrict__ kv, int ldkv, int koff, int voff,
    const int* __restrict__ rowptr, const int* __restrict__ esrc,
    int n, int g, const float* qf,
    float* a, float& lO)
{
    const int p0 = rowptr[n], p1 = rowptr[n + 1];
    float m = -1e30f, l = 0.f;
#pragma unroll
    for (int j = 0; j < 8; ++j) a[j] = 0.f;
    if (p0 < p1) {
        const int nit = (p1 - p0 + 3) >> 2;
        int p = p0 + g;
        bool valid = (p < p1);
        {
            const int s = esrc[valid ? p : (p1 - 1)];
            const unsigned short* rp = kv + (size_t)s * ldkv;
            uint4 kp = *(const uint4*)(rp + koff);
            uint4 vp = *(const uint4*)(rp + voff);
            for (int it = 0; it < nit; ++it) {
                const uint4 kc = kp, vc = vp;
                const bool vld = valid;
                p += 4;
                if (it + 1 < nit) {                 // prefetch next 4 edges
                    valid = (p < p1);
                    const int s2 = esrc[valid ? p : (p1 - 1)];
                    const unsigned short* r2 = kv + (size_t)s2 * ldkv;
                    kp = *(const uint4*)(r2 + koff);
                    vp = *(const uint4*)(r2 + voff);
                }
                float al = qf[0] * blo(kc.x) + qf[1] * bhi(kc.x);
                al += qf[2] * blo(kc.y) + qf[3] * bhi(kc.y);
                al += qf[4] * blo(kc.z) + qf[5] * bhi(kc.z);
                al += qf[6] * blo(kc.w) + qf[7] * bhi(kc.w);
                al += __shfl_xor(al, 1, 64);
                al += __shfl_xor(al, 2, 64);
                al = vld ? al : -2e30f;
                const float nm  = fmaxf(m, al);
                const float scl = __expf(m - nm);
                const float w   = __expf(al - nm);
                l = l * scl + w;
                a[0] = a[0] * scl + w * blo(vc.x);
                a[1] = a[1] * scl + w * bhi(vc.x);
                a[2] = a[2] * scl + w * blo(vc.y);
                a[3] = a[3] * scl + w * bhi(vc.y);
                a[4] = a[4] * scl + w * blo(vc.z);
                a[5] = a[5] * scl + w * bhi(vc.z);
                a[6] = a[6] * scl + w * blo(vc.w);
                a[7] = a[7] * scl + w * bhi(vc.w);
                m = nm;
            }
        }
    }
    // ---- merge the 4 per-group states ----
    float mo = fmaxf(m, __shfl_xor(m, 16, 64));
    const float M = fmaxf(mo, __shfl_xor(mo, 32, 64));
    const float sc = __expf(m - M);
    l *= sc;
#pragma unroll
    for (int j = 0; j < 8; ++j) a[j] *= sc;
    l += __shfl_xor(l, 16, 64);
    l += __shfl_xor(l, 32, 64);
#pragma unroll
    for (int j = 0; j < 8; ++j) {
        a[j] += __shfl_xor(a[j], 16, 64);
        a[j] += __shfl_xor(a[j], 32, 64);
    }
    lO = l;
}

// ---------------------------------------------------------------------------
// FUSED attention + out-proj. Block = 128 dst nodes of one type.
// Blocks [0, yb0): type1 (relations 0+2); [yb0, ...): type0 (relation 1).
// Phase 1: wave w computes attention for local nodes w*32..w*32+31, gelu,
//          bf16-pack -> LDS (XOR swizzle `^ (local&7)<<4` on the 16B slot —
//          without it, phase-2 ds_read_b128 is a 16-way bank conflict).
// Phase 2: out-proj MFMA with B-fragments from LDS; skip-mix epilogue writes
//          out (NT fp32) + hbf (bf16, next layer's input).
// OOB columns hold garbage in LDS; MFMA columns are independent and the
// epilogue skips node >= M, so valid outputs are unaffected.
// ---------------------------------------------------------------------------
__global__ __launch_bounds__(256) void hgt_attn_outproj(
    const unsigned short* __restrict__ qkv0,
    const unsigned short* __restrict__ qkv1,
    const int* __restrict__ rp1, const int* __restrict__ es1,   // dst t0
    const int* __restrict__ rp0, const int* __restrict__ es0,   // dst t1, rel0
    const int* __restrict__ rp2, const int* __restrict__ es2,   // dst t1, rel2
    const unsigned short* __restrict__ Wp, const float* __restrict__ biasP,
    int wblk0, int wblk1,
    unsigned short* __restrict__ hb0, unsigned short* __restrict__ hb1,
    float* __restrict__ outp0, float* __restrict__ outp1, int ldcf,
    const float* __restrict__ skipP,
    int M0, int M1, int yb0)
{
    __shared__ __align__(16) unsigned short lds[128 * 128];   // 32 KB
    const int tid = threadIdx.x;
    const int wid = tid >> 6, lane = tid & 63;
    const int u = lane & 15, g = lane >> 4;
    const int uo = u * 8;
    const int b = blockIdx.x;
    const int is1 = (b < yb0) ? 1 : 0;
    const int r0 = (is1 ? b : (b - yb0)) * 128;
    const int M  = is1 ? M1 : M0;

    // ---- phase 1: attention -> LDS ----
    for (int j = 0; j < 32; ++j) {
        const int local = wid * 32 + j;
        const int n = r0 + local;
        if (n < M) {
            float o[8];
            if (is1) {
                const uint4 qp = *(const uint4*)(qkv1 + (size_t)n * 640 + uo);
                float qf[8];
                qf[0] = blo(qp.x); qf[1] = bhi(qp.x);
                qf[2] = blo(qp.y); qf[3] = bhi(qp.y);
                qf[4] = blo(qp.z); qf[5] = bhi(qp.z);
                qf[6] = blo(qp.w); qf[7] = bhi(qp.w);
                float ax[8], ay[8], lx, ly;
                attn_loop4(qkv0, 384, 128 + uo, 256 + uo, rp0, es0, n, g, qf, ax, lx);
                attn_loop4(qkv1, 640, 384 + uo, 512 + uo, rp2, es2, n, g, qf, ay, ly);
                const float ix = 1.0f / (lx + 1e-16f);
                const float iy = 1.0f / (ly + 1e-16f);
#pragma unroll
                for (int k = 0; k < 8; ++k) o[k] = gelu_f(ax[k] * ix + ay[k] * iy);
            } else {
                const uint4 qp = *(const uint4*)(qkv0 + (size_t)n * 384 + uo);
                float qf[8];
                qf[0] = blo(qp.x); qf[1] = bhi(qp.x);
                qf[2] = blo(qp.y); qf[3] = bhi(qp.y);
                qf[4] = blo(qp.z); qf[5] = bhi(qp.z);
                qf[6] = blo(qp.w); qf[7] = bhi(qp.w);
                float av[8], lv;
                attn_loop4(qkv1, 640, 128 + uo, 256 + uo, rp1, es1, n, g, qf, av, lv);
                const float inv = 1.0f / (lv + 1e-16f);
#pragma unroll
                for (int k = 0; k < 8; ++k) o[k] = gelu_f(av[k] * inv);
            }
            if (g == 0) {
                const int byte = local * 256 + ((u * 16) ^ ((local & 7) << 4));
                *(uint4*)((char*)lds + byte) =
                    make_uint4(pk2(o[0], o[1]), pk2(o[2], o[3]),
                               pk2(o[4], o[5]), pk2(o[6], o[7]));
            }
        }
    }
    __syncthreads();

    // ---- phase 2: out-proj GEMM from LDS + skip-mix epilogue ----
    const int ow = (wid >> 1) * 64;
    const int nw = (wid & 1) * 64;
    const int lm = lane & 15;
    const int kq = lane >> 4;
    const int wblk = is1 ? wblk1 : wblk0;
    unsigned short* Hb = is1 ? hb1 : hb0;
    float* Cf = is1 ? outp1 : outp0;
    const float sv = skipP[is1];
    const float aa = 1.0f / (1.0f + __expf(-sv));
    const float ab = 1.0f - aa;

    short8 wf[4][4];
    const unsigned short* wbase = Wp + (size_t)wblk * 16384;
#pragma unroll
    for (int mi = 0; mi < 4; ++mi) {
        const int mt = (ow >> 4) + mi;
#pragma unroll
        for (int kt = 0; kt < 4; ++kt)
            wf[mi][kt] = *(const short8*)(wbase + (((mt * 4 + kt) * 64 + lane) << 3));
    }

    f32x4 acc[4][4];
#pragma unroll
    for (int ni = 0; ni < 4; ++ni)
#pragma unroll
        for (int mi = 0; mi < 4; ++mi)
            acc[ni][mi] = (f32x4){0.f, 0.f, 0.f, 0.f};

#pragma unroll
    for (int ni = 0; ni < 4; ++ni) {
        const int local = nw + ni * 16 + lm;
        short8 bl[4];
#pragma unroll
        for (int kt = 0; kt < 4; ++kt) {
            const int byte = local * 256 + ((kt * 64 + kq * 16) ^ ((local & 7) << 4));
            bl[kt] = *(const short8*)((const char*)lds + byte);
        }
#pragma unroll
        for (int kt = 0; kt < 4; ++kt)
#pragma unroll
            for (int mi = 0; mi < 4; ++mi)
                acc[ni][mi] = __builtin_amdgcn_mfma_f32_16x16x32_bf16(
                    wf[mi][kt], bl[kt], acc[ni][mi], 0, 0, 0);
    }

    float4 b4[4];
#pragma unroll
    for (int mi = 0; mi < 4; ++mi)
        b4[mi] = *(const float4*)(biasP + wblk * 128 + ow + mi * 16 + kq * 4);

#pragma unroll
    for (int ni = 0; ni < 4; ++ni) {
        const int node = r0 + nw + ni * 16 + lm;
        if (node >= M) continue;
#pragma unroll
        for (int mi = 0; mi < 4; ++mi) {
            const int oc = ow + mi * 16 + kq * 4;
            float v0 = acc[ni][mi][0] + b4[mi].x;
            float v1 = acc[ni][mi][1] + b4[mi].y;
            float v2 = acc[ni][mi][2] + b4[mi].z;
            float v3 = acc[ni][mi][3] + b4[mi].w;
            uint2 hp = *(const uint2*)(Hb + (size_t)node * 128 + oc);
            v0 = aa * v0 + ab * blo(hp.x);
            v1 = aa * v1 + ab * bhi(hp.x);
            v2 = aa * v2 + ab * blo(hp.y);
            v3 = aa * v3 + ab * bhi(hp.y);
            nt_st_f32x4(Cf + (size_t)node * ldcf + oc, v0, v1, v2, v3);
            *(uint2*)(Hb + (size_t)node * 128 + oc) =
                make_uint2(pk2(v0, v1), pk2(v2, v3));
        }
    }
}

// ---------------------------------------------------------------------------
// prep: edge histogram (grid.y 0..2) + weight pack (grid.y == 3, x < 22).
// ---------------------------------------------------------------------------
__global__ void hgt_prep(
    const float* __restrict__ W_in, const float* __restrict__ b_in,
    const float* __restrict__ Wk, const float* __restrict__ bk,
    const float* __restrict__ Wq, const float* __restrict__ bq,
    const float* __restrict__ Wv, const float* __restrict__ bv,
    const float* __restrict__ Wa, const float* __restrict__ ba,
    const float* __restrict__ a_rel, const float* __restrict__ m_rel,
    const float* __restrict__ p_rel,
    unsigned short* __restrict__ Bp, float* __restrict__ bp,
    const int* __restrict__ d0, const int* __restrict__ d1,
    const int* __restrict__ d2, int E, int N0v, int N1v,
    int* __restrict__ deg)
{
    if (blockIdx.y < 3) {
        const int r = blockIdx.y;
        const int e = blockIdx.x * 256 + threadIdx.x;
        if (e >= E) return;
        const int* dd = (r == 0) ? d0 : (r == 1) ? d1 : d2;
        const int doff = (r == 0) ? 0 : (r == 1) ? N1v : (N1v + N0v);
        atomicAdd(&deg[doff + dd[e]], 1);
        return;
    }
    const int bid = blockIdx.x;
    if (bid >= 22) return;

    const float* Wsrc = nullptr;
    const float* bsrc = nullptr;
    int l = -1, r = 0, kv = 0;
    if      (bid <  2) { Wsrc = W_in + (size_t)bid * 16384; bsrc = b_in + bid * 128; }
    else if (bid == 2) { Wsrc = Wq;                bsrc = bq; }
    else if (bid <= 4) { l = 0; r = 0; kv = bid - 3; }
    else if (bid == 5) { Wsrc = Wq + 16384;        bsrc = bq + 128; }
    else if (bid <= 7) { l = 0; r = 1; kv = bid - 6; }
    else if (bid <= 9) { l = 0; r = 2; kv = bid - 8; }
    else if (bid == 10){ Wsrc = Wa;                bsrc = ba; }
    else if (bid == 11){ Wsrc = Wa + 16384;        bsrc = ba + 128; }
    else if (bid == 12){ Wsrc = Wq + 2 * 16384;    bsrc = bq + 256; }
    else if (bid <= 14){ l = 1; r = 0; kv = bid - 13; }
    else if (bid == 15){ Wsrc = Wq + 3 * 16384;    bsrc = bq + 384; }
    else if (bid <= 17){ l = 1; r = 1; kv = bid - 16; }
    else if (bid <= 19){ l = 1; r = 2; kv = bid - 18; }
    else if (bid == 20){ Wsrc = Wa + 2 * 16384;    bsrc = ba + 256; }
    else               { Wsrc = Wa + 3 * 16384;    bsrc = ba + 384; }

    const bool iscw = (l >= 0);
    const float* rel = nullptr;
    if (iscw) {
        const int st = (r == 0) ? 0 : 1;
        Wsrc = (kv ? Wv : Wk) + (size_t)(l * 2 + st) * 16384;
        bsrc = (kv ? bv : bk) + (l * 2 + st) * 128;
        rel  = (kv ? m_rel : a_rel) + (size_t)(l * 3 + r) * 4096;
    }

    for (int i = threadIdx.x; i < 16384; i += 256) {
        const int mt = i >> 11, kt = (i >> 9) & 3, ln = (i >> 3) & 63, j = i & 7;
        const int m = mt * 16 + (ln & 15);              // outch
        const int k = kt * 32 + (ln >> 4) * 8 + j;      // inch
        float v;
        if (!iscw) {
            v = Wsrc[k * 128 + m];
        } else {
            const int h = m >> 5, e = m & 31;
            const float fac = kv ? 1.0f
                : p_rel[(l * 3 + r) * 4 + h] * 0.17677669529663687f;
            const float* wr = Wsrc + (size_t)k * 128 + h * 32;
            const float* rc = rel + h * 1024 + e;
            float s = 0.f;
#pragma unroll
            for (int d = 0; d < 32; ++d) s = fmaf(wr[d], rc[d * 32], s);
            v = s * fac;
        }
        Bp[(size_t)bid * 16384 + i] = f2b(v);
    }
    if (threadIdx.x < 128) {
        const int n = threadIdx.x;
        float v;
        if (!iscw) {
            v = bsrc[n];
        } else {
            const int h = n >> 5, e = n & 31;
            const float fac = kv ? 1.0f
                : p_rel[(l * 3 + r) * 4 + h] * 0.17677669529663687f;
            const float* rc = rel + h * 1024 + e;
            float s = 0.f;
#pragma unroll
            for (int d = 0; d < 32; ++d) s = fmaf(bsrc[h * 32 + d], rc[d * 32], s);
            v = s * fac;
        }
        bp[bid * 128 + n] = v;
    }
}

// --------------------- CSR construction ------------------------------------
// deg layout: [r0: N1][r1: N0][r2: N1]; rowptr: [N1+1][N0+1][N1+1]
__global__ void hgt_scan1(const int* __restrict__ deg, int* __restrict__ rowptr,
                          int* __restrict__ bsums, int N0v, int N1v)
{
    const int r = blockIdx.y;
    const int Nd = (r == 1) ? N0v : N1v;
    const int n  = Nd + 1;
    if (blockIdx.x * 512 >= n) return;
    const int doff = (r == 0) ? 0 : (r == 1) ? N1v : (N1v + N0v);
    const int roff = (r == 0) ? 0 : (r == 1) ? (N1v + 1) : (N1v + N0v + 2);
    __shared__ int s[512];
    const int tid = threadIdx.x;
    const int i = blockIdx.x * 512 + tid;
    const int v = (i < Nd) ? deg[doff + i] : 0;
    s[tid] = v;
    __syncthreads();
    for (int off = 1; off < 512; off <<= 1) {
        const int t = (tid >= off) ? s[tid - off] : 0;
        __syncthreads();
        s[tid] += t;
        __syncthreads();
    }
    if (i < n) rowptr[roff + i] = s[tid] - v;       // exclusive
    if (tid == 511) bsums[r * 256 + blockIdx.x] = s[511];
}

// scan2 folded in: each block reduces bsums[r*256 + 0..bx) itself.
__global__ void hgt_scan23(int* __restrict__ rowptr, const int* __restrict__ bsums,
                           int N0v, int N1v)
{
    const int r = blockIdx.y;
    const int n = ((r == 1) ? N0v : N1v) + 1;
    if (blockIdx.x * 512 >= n) return;
    const int roff = (r == 0) ? 0 : (r == 1) ? (N1v + 1) : (N1v + N0v + 2);
    const int tid = threadIdx.x;
    int v = (tid < (int)blockIdx.x) ? bsums[r * 256 + tid] : 0;   // bx <= 196 < 512
#pragma unroll
    for (int o = 1; o < 64; o <<= 1) v += __shfl_xor(v, o, 64);
    __shared__ int ws[8];
    if ((tid & 63) == 0) ws[tid >> 6] = v;
    __syncthreads();
    int base = 0;
#pragma unroll
    for (int k = 0; k < 8; ++k) base += ws[k];
    const int i = blockIdx.x * 512 + tid;
    if (i < n) rowptr[roff + i] += base;
}

// fill fused with in-proj GEMM: first nGemm blocks do the GEMM, the rest
// scatter edge sources into CSR order (independent work, hidden under GEMM).
__global__ __launch_bounds__(256) void hgt_fill_inproj(
    const int* __restrict__ s0, const int* __restrict__ d0,
    const int* __restrict__ s1, const int* __restrict__ d1,
    const int* __restrict__ s2, const int* __restrict__ d2,
    int E, int N0v, int N1v,
    const int* __restrict__ rowptr, int* __restrict__ cnt,
    int* __restrict__ esrc, int eb,
    const float* __restrict__ x0, const float* __restrict__ x1,
    const unsigned short* __restrict__ Wp, const float* __restrict__ biasP,
    unsigned short* __restrict__ hb0, unsigned short* __restrict__ hb1,
    float* __restrict__ outp, int nGemm, int yb0)
{
    const int b = blockIdx.x;
    if (b < nGemm) {
        gemm_body<1, 1, 0>(b, x0, x1, 128, Wp, biasP, 0, 1, 1, 1,
                           hb0, hb1, 128, 128,
                           outp, outp + (size_t)N0v * OLD, OLD,
                           N0v, N1v, yb0);
        return;
    }
    const int bb = b - nGemm;
    const int r = bb / eb;
    const int e = (bb - r * eb) * 256 + (int)threadIdx.x;
    if (e >= E) return;
    const int* ss = (r == 0) ? s0 : (r == 1) ? s1 : s2;
    const int* dd = (r == 0) ? d0 : (r == 1) ? d1 : d2;
    const int doff = (r == 0) ? 0 : (r == 1) ? N1v : (N1v + N0v);
    const int roff = (r == 0) ? 0 : (r == 1) ? (N1v + 1) : (N1v + N0v + 2);
    const int d = dd[e];
    const int pos = atomicAdd(&cnt[doff + d], 1);
    esrc[(size_t)r * E + rowptr[roff + d] + pos] = ss[e];
}

// ---------------------------------------------------------------------------
extern "C" void kernel_launch(void* const* d_in, const int* in_sizes, int n_in,
                              void* d_out, int out_size, void* d_ws, size_t ws_size,
                              hipStream_t stream)
{
    const float* x0  = (const float*)d_in[0];
    const float* x1  = (const float*)d_in[1];
    const int* src0 = (const int*)d_in[2];
    const int* dst0 = (const int*)d_in[3];
    const int* src1 = (const int*)d_in[4];
    const int* dst1 = (const int*)d_in[5];
    const int* src2 = (const int*)d_in[6];
    const int* dst2 = (const int*)d_in[7];
    const float* W_in = (const float*)d_in[8];
    const float* b_in = (const float*)d_in[9];
    const float* Wk = (const float*)d_in[10];
    const float* bk = (const float*)d_in[11];
    const float* Wq = (const float*)d_in[12];
    const float* bq = (const float*)d_in[13];
    const float* Wv = (const float*)d_in[14];
    const float* bv = (const float*)d_in[15];
    const float* Wa = (const float*)d_in[16];
    const float* ba = (const float*)d_in[17];
    const float* skip = (const float*)d_in[18];
    const float* a_rel = (const float*)d_in[19];
    const float* m_rel = (const float*)d_in[20];
    const float* p_rel = (const float*)d_in[21];

    const int N0 = in_sizes[0] / HID;   // 100000
    const int N1 = in_sizes[1] / HID;   // 50000
    const int E  = in_sizes[2];         // 200000
    float* out = (float*)d_out;
    (void)n_in; (void)out_size; (void)ws_size;

    // ---- workspace carve (256B aligned) ----
    char* p = (char*)d_ws;
    auto carve = [&](size_t bytes) -> char* {
        char* q = p;
        p += (bytes + 255) & ~(size_t)255;
        return q;
    };
    unsigned short* hbf  = (unsigned short*)carve((size_t)(N0 + N1) * 128 * 2);
    unsigned short* qkv0 = (unsigned short*)carve((size_t)N0 * 384 * 2);
    unsigned short* qkv1 = (unsigned short*)carve((size_t)N1 * 640 * 2);
    unsigned short* packW = (unsigned short*)carve((size_t)22 * 16384 * 2);
    float* packb = (float*)carve((size_t)22 * 128 * 4);
    int* rowptr = (int*)carve((size_t)(N0 + 2 * N1 + 3) * 4);
    int* esrc   = (int*)carve((size_t)3 * E * 4);
    // zero-region: deg + cnt + bsums (one memset)
    char* zbase = carve(0);
    int* deg   = (int*)carve((size_t)(N0 + 2 * N1) * 4);
    int* cnt   = (int*)carve((size_t)(N0 + 2 * N1) * 4);
    int* bsums = (int*)carve(3 * 256 * 4);
    const size_t zbytes = (size_t)((char*)(bsums + 3 * 256) - zbase);

    unsigned short* hbf1 = hbf + (size_t)N0 * 128;
    const int* rp0 = rowptr;                      // dst t1 (rel0)
    const int* rp1 = rowptr + (N1 + 1);           // dst t0 (rel1)
    const int* rp2 = rowptr + (N1 + N0 + 2);      // dst t1 (rel2)
    const int* es0 = esrc;
    const int* es1 = esrc + (size_t)E;
    const int* es2 = esrc + (size_t)2 * E;

    const int eb  = (E + 255) / 256;
    const int nbx = (N0 + 1 + 511) / 512;
    const int mbN0 = (N0 + 127) / 128;
    const int mbN1 = (N1 + 127) / 128;
    const int nGemm = mbN0 + mbN1;

    // ---- d1: zero deg/cnt/bsums ----
    hipMemsetAsync(zbase, 0, zbytes, stream);

    // ---- d2: histogram + weight pack (fused) ----
    hgt_prep<<<dim3(eb, 4), 256, 0, stream>>>(
        W_in, b_in, Wk, bk, Wq, bq, Wv, bv, Wa, ba,
        a_rel, m_rel, p_rel, packW, packb,
        dst0, dst1, dst2, E, N0, N1, deg);

    // ---- d3/d4: scans ----
    hgt_scan1 <<<dim3(nbx, 3), 512, 0, stream>>>(deg, rowptr, bsums, N0, N1);
    hgt_scan23<<<dim3(nbx, 3), 512, 0, stream>>>(rowptr, bsums, N0, N1);

    // ---- d5: CSR fill + in-proj GEMM (fused) ----
    hgt_fill_inproj<<<nGemm + 3 * eb, 256, 0, stream>>>(
        src0, dst0, src1, dst1, src2, dst2, E, N0, N1,
        rowptr, cnt, (int*)esrc, eb,
        x0, x1, packW, packb, hbf, hbf1, out, nGemm, mbN0);

    for (int l = 0; l < 2; ++l) {
        const int qkv0_blk = l ? 12 : 2;
        const int qkv1_blk = l ? 15 : 5;
        const int out0_blk = l ? 20 : 10;
        const int out1_blk = l ? 21 : 11;

        // ---- merged q|kr|vr GEMM (type1 first: 5 col-blocks, heavier) ----
        mfma_gemm<0, 0, 1><<<nGemm, 256, 0, stream>>>(
            hbf1, hbf, 128, packW, packb,
            qkv1_blk, qkv0_blk, 5, 3,
            qkv1, qkv0, 640, 384,
            nullptr, nullptr, 0,
            N1, N0, mbN1);

        // ---- FUSED attention + out-proj (type1 blocks first) ----
        hgt_attn_outproj<<<mbN1 + mbN0, 256, 0, stream>>>(
            qkv0, qkv1, rp1, es1, rp0, es0, rp2, es2,
            packW, packb, out0_blk, out1_blk,
            hbf, hbf1,
            out + (size_t)(l + 1) * 128,
            out + (size_t)N0 * OLD + (size_t)(l + 1) * 128, OLD,
            skip + l * 2, N0, N1, mbN1);
    }
}

// Round 8
// 817.063 us; speedup vs baseline: 1.1806x; 1.1806x over previous
//
#include <hip/hip_runtime.h>
#include <math.h>

// ---------------------------------------------------------------------------
// HGT on MI355X — round 9.
//  * Base: r6 exactly (834 µs best; BRES qkv GEMM, NT out/x hints, separate
//    attn). r8's attn+outproj fusion regressed (210 µs/dispatch, occupancy
//    25%, serial 32-nodes/wave) and is reverted.
//  * Single change: distributed gelu epilogue in hgt_attn. After the merge
//    butterfly all 4 groups hold identical a[]/l, so each group g computes
//    gelu for channels 2g,2g+1 and writes its own 4-B word — full-wave gelu
//    instead of 16 lanes doing 8 erff each while 48 lanes idle (r8 counters:
//    VALUBusy 57% with MfmaUtil ~1% -> idle-lane erff was the VALU sink).
// ---------------------------------------------------------------------------

#define HID 128
#define OLD 384   // d_out row stride = 3*HID

typedef __attribute__((ext_vector_type(8))) short short8;
typedef __attribute__((ext_vector_type(4))) float f32x4;

__device__ __forceinline__ unsigned short f2b(float f) {
    unsigned u = __float_as_uint(f);
    u += 0x7fffu + ((u >> 16) & 1u);          // RNE
    return (unsigned short)(u >> 16);
}
__device__ __forceinline__ unsigned pk2(float a, float b) {
    return (unsigned)f2b(a) | ((unsigned)f2b(b) << 16);
}
__device__ __forceinline__ float blo(unsigned u) { return __uint_as_float(u << 16); }
__device__ __forceinline__ float bhi(unsigned u) { return __uint_as_float(u & 0xffff0000u); }
__device__ __forceinline__ float gelu_f(float x) {
    return 0.5f * x * (1.0f + erff(x * 0.70710678118654752f));
}

// non-temporal helpers (evict-first hint; keeps L3 for the hot working set)
__device__ __forceinline__ void nt_st_f32x4(float* p, float a, float b,
                                            float c, float d) {
    f32x4 v = {a, b, c, d};
    __builtin_nontemporal_store(v, (f32x4*)p);
}
__device__ __forceinline__ f32x4 nt_ld_f32x4(const float* p) {
    return __builtin_nontemporal_load((const f32x4*)p);
}

// ---------------------------------------------------------------------------
// MFMA GEMM body (transposed operands): D = W^T-as-A x activations-as-B.
// Wp frag-packed per 128x128 block: [mt(8)][kt(4)][lane(64)][j(8)].
// Merged over two node types: first yb0 blocks = slot 0, rest = slot 1.
// ct loop (col-blocks) runs inside the block; BRES=1 keeps B-fragments
// register-resident across the ct loop.
// EPI 0: bf16 -> Cb[node*ldcb + ct*128 + oc]                       (qkv)
// EPI 1: relu; fp32 -> Cf[node*ldcf+oc], bf16 -> Cb[node*128+oc]   (in-proj)
// EPI 2: skip-mix with Hb (bf16,128); fp32 Cf + bf16 Cb            (out-proj)
// ---------------------------------------------------------------------------
template <int AFP32>
__device__ __forceinline__ void load_bfrag(short8 (&d)[4], const void* Aptr,
                                           int lda, int node, int kq)
{
    if (AFP32) {
        const float* ar = (const float*)Aptr + (size_t)node * lda;
#pragma unroll
        for (int kt = 0; kt < 4; ++kt) {
            f32x4 v0 = nt_ld_f32x4(ar + kt * 32 + kq * 8);
            f32x4 v1 = nt_ld_f32x4(ar + kt * 32 + kq * 8 + 4);
            short8 t;
            t[0] = (short)f2b(v0[0]); t[1] = (short)f2b(v0[1]);
            t[2] = (short)f2b(v0[2]); t[3] = (short)f2b(v0[3]);
            t[4] = (short)f2b(v1[0]); t[5] = (short)f2b(v1[1]);
            t[6] = (short)f2b(v1[2]); t[7] = (short)f2b(v1[3]);
            d[kt] = t;
        }
    } else {
        const unsigned short* ar = (const unsigned short*)Aptr + (size_t)node * lda;
#pragma unroll
        for (int kt = 0; kt < 4; ++kt)
            d[kt] = *(const short8*)(ar + kt * 32 + kq * 8);
    }
}

template <int AFP32, int EPI, int BRES>
__device__ __forceinline__ void gemm_body(
    int yb,
    const void* __restrict__ A0, const void* __restrict__ A1, int lda,
    const unsigned short* __restrict__ Wp, const float* __restrict__ biasP,
    int wblk0, int wblk1, int nct0, int nct1,
    unsigned short* __restrict__ Cb0, unsigned short* __restrict__ Cb1,
    int ldcb0, int ldcb1,
    float* __restrict__ Cf0, float* __restrict__ Cf1, int ldcf,
    const unsigned short* __restrict__ Hb0, const unsigned short* __restrict__ Hb1,
    const float* __restrict__ skipP,
    int M0, int M1, int yb0)
{
    const int tid  = threadIdx.x;
    const int wid  = tid >> 6;
    const int lane = tid & 63;
    const int ow = (wid >> 1) * 64;     // outch offset in 128-block
    const int nw = (wid & 1) * 64;      // node offset in 128-tile
    const int lm = lane & 15;
    const int kq = lane >> 4;

    const int t  = (yb >= yb0) ? 1 : 0;
    const int r0 = (t ? (yb - yb0) : yb) * 128;
    const int M    = t ? M1 : M0;
    const int nct  = t ? nct1 : nct0;
    const int wblk = t ? wblk1 : wblk0;
    const void* Aptr = t ? A1 : A0;
    unsigned short* Cb = t ? Cb1 : Cb0;
    const int ldcb = t ? ldcb1 : ldcb0;
    float* Cf = t ? Cf1 : Cf0;
    const unsigned short* Hb = t ? Hb1 : Hb0;

    // ---- B fragments (activations), optionally resident across ct loop ----
    short8 bres[4][4];
    if (BRES) {
#pragma unroll
        for (int ni = 0; ni < 4; ++ni) {
            int node = r0 + nw + ni * 16 + lm;
            node = (node < M) ? node : (M - 1);
            load_bfrag<AFP32>(bres[ni], Aptr, lda, node, kq);
        }
    }

    float aa = 0.f, ab = 0.f;
    if (EPI == 2) {
        const float sv = skipP[t];
        aa = 1.0f / (1.0f + __expf(-sv));
        ab = 1.0f - aa;
    }

    for (int ct = 0; ct < nct; ++ct) {
        const unsigned short* wbase = Wp + (size_t)(wblk + ct) * 16384;
        short8 wf[4][4];
#pragma unroll
        for (int mi = 0; mi < 4; ++mi) {
            const int mt = (ow >> 4) + mi;
#pragma unroll
            for (int kt = 0; kt < 4; ++kt)
                wf[mi][kt] = *(const short8*)(wbase + (((mt * 4 + kt) * 64 + lane) << 3));
        }

        f32x4 acc[4][4];    // [ni][mi]
#pragma unroll
        for (int ni = 0; ni < 4; ++ni)
#pragma unroll
            for (int mi = 0; mi < 4; ++mi)
                acc[ni][mi] = (f32x4){0.f, 0.f, 0.f, 0.f};

#pragma unroll
        for (int ni = 0; ni < 4; ++ni) {
            if (BRES) {
#pragma unroll
                for (int kt = 0; kt < 4; ++kt)
#pragma unroll
                    for (int mi = 0; mi < 4; ++mi)
                        acc[ni][mi] = __builtin_amdgcn_mfma_f32_16x16x32_bf16(
                            wf[mi][kt], bres[ni][kt], acc[ni][mi], 0, 0, 0);
            } else {
                int node = r0 + nw + ni * 16 + lm;
                node = (node < M) ? node : (M - 1);
                short8 bl[4];
                load_bfrag<AFP32>(bl, Aptr, lda, node, kq);
#pragma unroll
                for (int kt = 0; kt < 4; ++kt)
#pragma unroll
                    for (int mi = 0; mi < 4; ++mi)
                        acc[ni][mi] = __builtin_amdgcn_mfma_f32_16x16x32_bf16(
                            wf[mi][kt], bl[kt], acc[ni][mi], 0, 0, 0);
            }
        }

        // ---- epilogue: lane owns 4 consecutive outch per (ni,mi) ----
        float4 b4[4];
#pragma unroll
        for (int mi = 0; mi < 4; ++mi)
            b4[mi] = *(const float4*)(biasP + (wblk + ct) * 128 + ow + mi * 16 + kq * 4);

#pragma unroll
        for (int ni = 0; ni < 4; ++ni) {
            const int node = r0 + nw + ni * 16 + lm;
            if (node >= M) continue;
#pragma unroll
            for (int mi = 0; mi < 4; ++mi) {
                const int oc = ow + mi * 16 + kq * 4;
                float v0 = acc[ni][mi][0] + b4[mi].x;
                float v1 = acc[ni][mi][1] + b4[mi].y;
                float v2 = acc[ni][mi][2] + b4[mi].z;
                float v3 = acc[ni][mi][3] + b4[mi].w;
                if (EPI == 1) {
                    v0 = fmaxf(v0, 0.f); v1 = fmaxf(v1, 0.f);
                    v2 = fmaxf(v2, 0.f); v3 = fmaxf(v3, 0.f);
                }
                if (EPI == 2) {
                    uint2 hp = *(const uint2*)(Hb + (size_t)node * 128 + oc);
                    v0 = aa * v0 + ab * blo(hp.x);
                    v1 = aa * v1 + ab * bhi(hp.x);
                    v2 = aa * v2 + ab * blo(hp.y);
                    v3 = aa * v3 + ab * bhi(hp.y);
                }
                if (EPI != 0) {
                    nt_st_f32x4(Cf + (size_t)node * ldcf + oc, v0, v1, v2, v3);
                    *(uint2*)(Cb + (size_t)node * 128 + oc) =
                        make_uint2(pk2(v0, v1), pk2(v2, v3));
                } else {
                    *(uint2*)(Cb + (size_t)node * ldcb + ct * 128 + oc) =
                        make_uint2(pk2(v0, v1), pk2(v2, v3));
                }
            }
        }
    }
}

template <int AFP32, int EPI, int BRES>
__global__ __launch_bounds__(256) void mfma_gemm(
    const void* __restrict__ A0, const void* __restrict__ A1, int lda,
    const unsigned short* __restrict__ Wp, const float* __restrict__ biasP,
    int wblk0, int wblk1, int nct0, int nct1,
    unsigned short* __restrict__ Cb0, unsigned short* __restrict__ Cb1,
    int ldcb0, int ldcb1,
    float* __restrict__ Cf0, float* __restrict__ Cf1, int ldcf,
    const unsigned short* __restrict__ Hb0, const unsigned short* __restrict__ Hb1,
    const float* __restrict__ skipP,
    int M0, int M1, int yb0)
{
    gemm_body<AFP32, EPI, BRES>(blockIdx.x, A0, A1, lda, Wp, biasP,
        wblk0, wblk1, nct0, nct1, Cb0, Cb1, ldcb0, ldcb1,
        Cf0, Cf1, ldcf, Hb0, Hb1, skipP, M0, M1, yb0);
}

// ---------------------------------------------------------------------------
// Attention, 4 edges in parallel per wave.
// Lane = g*16 + u: group g (0..3) owns edge p0 + it*4 + g; lane u (0..15)
// owns channels u*8 .. u*8+7 (head = u>>2). Per-head dot reduced over the
// 4-lane quarter cluster (xor 1,2). Per-group online-softmax states merged
// at the end: global max (xor 16,32), local rescale, then sum butterfly.
// After the butterfly ALL groups hold identical a[]/l, so the epilogue
// distributes gelu across groups (g handles channels 2g,2g+1).
// ---------------------------------------------------------------------------
__device__ __forceinline__ void attn_loop4(
    const unsigned short* __restrict__ kv, int ldkv, int koff, int voff,
    const int* __restrict__ rowptr, const int* __restrict__ esrc,
    int n, int g, const float* qf,
    float* a, float& lO)
{
    const int p0 = rowptr[n], p1 = rowptr[n + 1];
    float m = -1e30f, l = 0.f;
#pragma unroll
    for (int j = 0; j < 8; ++j) a[j] = 0.f;
    if (p0 < p1) {
        const int nit = (p1 - p0 + 3) >> 2;
        int p = p0 + g;
        bool valid = (p < p1);
        {
            const int s = esrc[valid ? p : (p1 - 1)];
            const unsigned short* rp = kv + (size_t)s * ldkv;
            uint4 kp = *(const uint4*)(rp + koff);
            uint4 vp = *(const uint4*)(rp + voff);
            for (int it = 0; it < nit; ++it) {
                const uint4 kc = kp, vc = vp;
                const bool vld = valid;
                p += 4;
                if (it + 1 < nit) {                 // prefetch next 4 edges
                    valid = (p < p1);
                    const int s2 = esrc[valid ? p : (p1 - 1)];
                    const unsigned short* r2 = kv + (size_t)s2 * ldkv;
                    kp = *(const uint4*)(r2 + koff);
                    vp = *(const uint4*)(r2 + voff);
                }
                float al = qf[0] * blo(kc.x) + qf[1] * bhi(kc.x);
                al += qf[2] * blo(kc.y) + qf[3] * bhi(kc.y);
                al += qf[4] * blo(kc.z) + qf[5] * bhi(kc.z);
                al += qf[6] * blo(kc.w) + qf[7] * bhi(kc.w);
                al += __shfl_xor(al, 1, 64);
                al += __shfl_xor(al, 2, 64);
                al = vld ? al : -2e30f;
                const float nm  = fmaxf(m, al);
                const float scl = __expf(m - nm);
                const float w   = __expf(al - nm);
                l = l * scl + w;
                a[0] = a[0] * scl + w * blo(vc.x);
                a[1] = a[1] * scl + w * bhi(vc.x);
                a[2] = a[2] * scl + w * blo(vc.y);
                a[3] = a[3] * scl + w * bhi(vc.y);
                a[4] = a[4] * scl + w * blo(vc.z);
                a[5] = a[5] * scl + w * bhi(vc.z);
                a[6] = a[6] * scl + w * blo(vc.w);
                a[7] = a[7] * scl + w * bhi(vc.w);
                m = nm;
            }
        }
    }
    // ---- merge the 4 per-group states ----
    float mo = fmaxf(m, __shfl_xor(m, 16, 64));
    const float M = fmaxf(mo, __shfl_xor(mo, 32, 64));
    const float sc = __expf(m - M);
    l *= sc;
#pragma unroll
    for (int j = 0; j < 8; ++j) a[j] *= sc;
    l += __shfl_xor(l, 16, 64);
    l += __shfl_xor(l, 32, 64);
#pragma unroll
    for (int j = 0; j < 8; ++j) {
        a[j] += __shfl_xor(a[j], 16, 64);
        a[j] += __shfl_xor(a[j], 32, 64);
    }
    lO = l;
}

// merged: first nb1 blocks = dst type1 (r0 + r2, heavier), rest = dst type0
__global__ __launch_bounds__(256) void hgt_attn(
    const unsigned short* __restrict__ qkv0,
    const unsigned short* __restrict__ qkv1,
    const int* __restrict__ rp1, const int* __restrict__ es1,   // dst t0
    const int* __restrict__ rp0, const int* __restrict__ es0,   // dst t1, rel0
    const int* __restrict__ rp2, const int* __restrict__ es2,   // dst t1, rel2
    unsigned short* __restrict__ agg0, unsigned short* __restrict__ agg1,
    int N0, int N1, int nb1)
{
    const int wid = threadIdx.x >> 6, lane = threadIdx.x & 63;
    const int u = lane & 15, g = lane >> 4;
    const int uo = u * 8;
    const int c = 2 * g;                 // this group's channel pair
    const int b = blockIdx.x;
    float qf[8];
    if (b < nb1) {
        const int n = b * 4 + wid;
        if (n >= N1) return;
        const uint4 qp = *(const uint4*)(qkv1 + (size_t)n * 640 + uo);
        qf[0] = blo(qp.x); qf[1] = bhi(qp.x);
        qf[2] = blo(qp.y); qf[3] = bhi(qp.y);
        qf[4] = blo(qp.z); qf[5] = bhi(qp.z);
        qf[6] = blo(qp.w); qf[7] = bhi(qp.w);
        float ax[8], ay[8], lx, ly;
        attn_loop4(qkv0, 384, 128 + uo, 256 + uo, rp0, es0, n, g, qf, ax, lx);
        attn_loop4(qkv1, 640, 384 + uo, 512 + uo, rp2, es2, n, g, qf, ay, ly);
        const float ix = 1.0f / (lx + 1e-16f);
        const float iy = 1.0f / (ly + 1e-16f);
        *(unsigned*)(agg1 + (size_t)n * 128 + uo + c) =
            pk2(gelu_f(ax[c] * ix + ay[c] * iy),
                gelu_f(ax[c + 1] * ix + ay[c + 1] * iy));
    } else {
        const int n = (b - nb1) * 4 + wid;
        if (n >= N0) return;
        const uint4 qp = *(const uint4*)(qkv0 + (size_t)n * 384 + uo);
        qf[0] = blo(qp.x); qf[1] = bhi(qp.x);
        qf[2] = blo(qp.y); qf[3] = bhi(qp.y);
        qf[4] = blo(qp.z); qf[5] = bhi(qp.z);
        qf[6] = blo(qp.w); qf[7] = bhi(qp.w);
        float av[8], lv;
        attn_loop4(qkv1, 640, 128 + uo, 256 + uo, rp1, es1, n, g, qf, av, lv);
        const float inv = 1.0f / (lv + 1e-16f);
        *(unsigned*)(agg0 + (size_t)n * 128 + uo + c) =
            pk2(gelu_f(av[c] * inv), gelu_f(av[c + 1] * inv));
    }
}

// ---------------------------------------------------------------------------
// prep: edge histogram (grid.y 0..2) + weight pack (grid.y == 3, x < 22).
// Pack: 22 blocks of 128x128 -> bf16 A-fragment order; combined relation
// weights (W @ rel * fac) computed on the fly.
// Block order: [Win0,Win1, Wq00,cwK00,cwV00, Wq01,cwK01,cwV01,cwK02,cwV02,
//   Wa00,Wa01, Wq10,cwK10,cwV10, Wq11,cwK11,cwV11,cwK12,cwV12, Wa10,Wa11]
// ---------------------------------------------------------------------------
__global__ void hgt_prep(
    const float* __restrict__ W_in, const float* __restrict__ b_in,
    const float* __restrict__ Wk, const float* __restrict__ bk,
    const float* __restrict__ Wq, const float* __restrict__ bq,
    const float* __restrict__ Wv, const float* __restrict__ bv,
    const float* __restrict__ Wa, const float* __restrict__ ba,
    const float* __restrict__ a_rel, const float* __restrict__ m_rel,
    const float* __restrict__ p_rel,
    unsigned short* __restrict__ Bp, float* __restrict__ bp,
    const int* __restrict__ d0, const int* __restrict__ d1,
    const int* __restrict__ d2, int E, int N0v, int N1v,
    int* __restrict__ deg)
{
    if (blockIdx.y < 3) {
        const int r = blockIdx.y;
        const int e = blockIdx.x * 256 + threadIdx.x;
        if (e >= E) return;
        const int* dd = (r == 0) ? d0 : (r == 1) ? d1 : d2;
        const int doff = (r == 0) ? 0 : (r == 1) ? N1v : (N1v + N0v);
        atomicAdd(&deg[doff + dd[e]], 1);
        return;
    }
    const int bid = blockIdx.x;
    if (bid >= 22) return;

    const float* Wsrc = nullptr;
    const float* bsrc = nullptr;
    int l = -1, r = 0, kv = 0;
    if      (bid <  2) { Wsrc = W_in + (size_t)bid * 16384; bsrc = b_in + bid * 128; }
    else if (bid == 2) { Wsrc = Wq;                bsrc = bq; }
    else if (bid <= 4) { l = 0; r = 0; kv = bid - 3; }
    else if (bid == 5) { Wsrc = Wq + 16384;        bsrc = bq + 128; }
    else if (bid <= 7) { l = 0; r = 1; kv = bid - 6; }
    else if (bid <= 9) { l = 0; r = 2; kv = bid - 8; }
    else if (bid == 10){ Wsrc = Wa;                bsrc = ba; }
    else if (bid == 11){ Wsrc = Wa + 16384;        bsrc = ba + 128; }
    else if (bid == 12){ Wsrc = Wq + 2 * 16384;    bsrc = bq + 256; }
    else if (bid <= 14){ l = 1; r = 0; kv = bid - 13; }
    else if (bid == 15){ Wsrc = Wq + 3 * 16384;    bsrc = bq + 384; }
    else if (bid <= 17){ l = 1; r = 1; kv = bid - 16; }
    else if (bid <= 19){ l = 1; r = 2; kv = bid - 18; }
    else if (bid == 20){ Wsrc = Wa + 2 * 16384;    bsrc = ba + 256; }
    else               { Wsrc = Wa + 3 * 16384;    bsrc = ba + 384; }

    const bool iscw = (l >= 0);
    const float* rel = nullptr;
    if (iscw) {
        const int st = (r == 0) ? 0 : 1;
        Wsrc = (kv ? Wv : Wk) + (size_t)(l * 2 + st) * 16384;
        bsrc = (kv ? bv : bk) + (l * 2 + st) * 128;
        rel  = (kv ? m_rel : a_rel) + (size_t)(l * 3 + r) * 4096;
    }

    for (int i = threadIdx.x; i < 16384; i += 256) {
        const int mt = i >> 11, kt = (i >> 9) & 3, ln = (i >> 3) & 63, j = i & 7;
        const int m = mt * 16 + (ln & 15);              // outch
        const int k = kt * 32 + (ln >> 4) * 8 + j;      // inch
        float v;
        if (!iscw) {
            v = Wsrc[k * 128 + m];
        } else {
            const int h = m >> 5, e = m & 31;
            const float fac = kv ? 1.0f
                : p_rel[(l * 3 + r) * 4 + h] * 0.17677669529663687f;
            const float* wr = Wsrc + (size_t)k * 128 + h * 32;
            const float* rc = rel + h * 1024 + e;
            float s = 0.f;
#pragma unroll
            for (int d = 0; d < 32; ++d) s = fmaf(wr[d], rc[d * 32], s);
            v = s * fac;
        }
        Bp[(size_t)bid * 16384 + i] = f2b(v);
    }
    if (threadIdx.x < 128) {
        const int n = threadIdx.x;
        float v;
        if (!iscw) {
            v = bsrc[n];
        } else {
            const int h = n >> 5, e = n & 31;
            const float fac = kv ? 1.0f
                : p_rel[(l * 3 + r) * 4 + h] * 0.17677669529663687f;
            const float* rc = rel + h * 1024 + e;
            float s = 0.f;
#pragma unroll
            for (int d = 0; d < 32; ++d) s = fmaf(bsrc[h * 32 + d], rc[d * 32], s);
            v = s * fac;
        }
        bp[bid * 128 + n] = v;
    }
}

// --------------------- CSR construction ------------------------------------
// deg layout: [r0: N1][r1: N0][r2: N1]; rowptr: [N1+1][N0+1][N1+1]
__global__ void hgt_scan1(const int* __restrict__ deg, int* __restrict__ rowptr,
                          int* __restrict__ bsums, int N0v, int N1v)
{
    const int r = blockIdx.y;
    const int Nd = (r == 1) ? N0v : N1v;
    const int n  = Nd + 1;
    if (blockIdx.x * 512 >= n) return;
    const int doff = (r == 0) ? 0 : (r == 1) ? N1v : (N1v + N0v);
    const int roff = (r == 0) ? 0 : (r == 1) ? (N1v + 1) : (N1v + N0v + 2);
    __shared__ int s[512];
    const int tid = threadIdx.x;
    const int i = blockIdx.x * 512 + tid;
    const int v = (i < Nd) ? deg[doff + i] : 0;
    s[tid] = v;
    __syncthreads();
    for (int off = 1; off < 512; off <<= 1) {
        const int t = (tid >= off) ? s[tid - off] : 0;
        __syncthreads();
        s[tid] += t;
        __syncthreads();
    }
    if (i < n) rowptr[roff + i] = s[tid] - v;       // exclusive
    if (tid == 511) bsums[r * 256 + blockIdx.x] = s[511];
}

// scan2 folded in: each block reduces bsums[r*256 + 0..bx) itself.
__global__ void hgt_scan23(int* __restrict__ rowptr, const int* __restrict__ bsums,
                           int N0v, int N1v)
{
    const int r = blockIdx.y;
    const int n = ((r == 1) ? N0v : N1v) + 1;
    if (blockIdx.x * 512 >= n) return;
    const int roff = (r == 0) ? 0 : (r == 1) ? (N1v + 1) : (N1v + N0v + 2);
    const int tid = threadIdx.x;
    int v = (tid < (int)blockIdx.x) ? bsums[r * 256 + tid] : 0;   // bx <= 196 < 512
#pragma unroll
    for (int o = 1; o < 64; o <<= 1) v += __shfl_xor(v, o, 64);
    __shared__ int ws[8];
    if ((tid & 63) == 0) ws[tid >> 6] = v;
    __syncthreads();
    int base = 0;
#pragma unroll
    for (int k = 0; k < 8; ++k) base += ws[k];
    const int i = blockIdx.x * 512 + tid;
    if (i < n) rowptr[roff + i] += base;
}

// fill fused with in-proj GEMM: first nGemm blocks do the GEMM, the rest
// scatter edge sources into CSR order (independent work, hidden under GEMM).
__global__ __launch_bounds__(256) void hgt_fill_inproj(
    const int* __restrict__ s0, const int* __restrict__ d0,
    const int* __restrict__ s1, const int* __restrict__ d1,
    const int* __restrict__ s2, const int* __restrict__ d2,
    int E, int N0v, int N1v,
    const int* __restrict__ rowptr, int* __restrict__ cnt,
    int* __restrict__ esrc, int eb,
    const float* __restrict__ x0, const float* __restrict__ x1,
    const unsigned short* __restrict__ Wp, const float* __restrict__ biasP,
    unsigned short* __restrict__ hb0, unsigned short* __restrict__ hb1,
    float* __restrict__ outp, int nGemm, int yb0)
{
    const int b = blockIdx.x;
    if (b < nGemm) {
        gemm_body<1, 1, 0>(b, x0, x1, 128, Wp, biasP, 0, 1, 1, 1,
                           hb0, hb1, 128, 128,
                           outp, outp + (size_t)N0v * OLD, OLD,
                           nullptr, nullptr, nullptr, N0v, N1v, yb0);
        return;
    }
    const int bb = b - nGemm;
    const int r = bb / eb;
    const int e = (bb - r * eb) * 256 + (int)threadIdx.x;
    if (e >= E) return;
    const int* ss = (r == 0) ? s0 : (r == 1) ? s1 : s2;
    const int* dd = (r == 0) ? d0 : (r == 1) ? d1 : d2;
    const int doff = (r == 0) ? 0 : (r == 1) ? N1v : (N1v + N0v);
    const int roff = (r == 0) ? 0 : (r == 1) ? (N1v + 1) : (N1v + N0v + 2);
    const int d = dd[e];
    const int pos = atomicAdd(&cnt[doff + d], 1);
    esrc[(size_t)r * E + rowptr[roff + d] + pos] = ss[e];
}

// ---------------------------------------------------------------------------
extern "C" void kernel_launch(void* const* d_in, const int* in_sizes, int n_in,
                              void* d_out, int out_size, void* d_ws, size_t ws_size,
                              hipStream_t stream)
{
    const float* x0  = (const float*)d_in[0];
    const float* x1  = (const float*)d_in[1];
    const int* src0 = (const int*)d_in[2];
    const int* dst0 = (const int*)d_in[3];
    const int* src1 = (const int*)d_in[4];
    const int* dst1 = (const int*)d_in[5];
    const int* src2 = (const int*)d_in[6];
    const int* dst2 = (const int*)d_in[7];
    const float* W_in = (const float*)d_in[8];
    const float* b_in = (const float*)d_in[9];
    const float* Wk = (const float*)d_in[10];
    const float* bk = (const float*)d_in[11];
    const float* Wq = (const float*)d_in[12];
    const float* bq = (const float*)d_in[13];
    const float* Wv = (const float*)d_in[14];
    const float* bv = (const float*)d_in[15];
    const float* Wa = (const float*)d_in[16];
    const float* ba = (const float*)d_in[17];
    const float* skip = (const float*)d_in[18];
    const float* a_rel = (const float*)d_in[19];
    const float* m_rel = (const float*)d_in[20];
    const float* p_rel = (const float*)d_in[21];

    const int N0 = in_sizes[0] / HID;   // 100000
    const int N1 = in_sizes[1] / HID;   // 50000
    const int E  = in_sizes[2];         // 200000
    float* out = (float*)d_out;
    (void)n_in; (void)out_size; (void)ws_size;

    // ---- workspace carve (256B aligned) ----
    char* p = (char*)d_ws;
    auto carve = [&](size_t bytes) -> char* {
        char* q = p;
        p += (bytes + 255) & ~(size_t)255;
        return q;
    };
    unsigned short* hbf  = (unsigned short*)carve((size_t)(N0 + N1) * 128 * 2);
    unsigned short* qkv0 = (unsigned short*)carve((size_t)N0 * 384 * 2);
    unsigned short* qkv1 = (unsigned short*)carve((size_t)N1 * 640 * 2);
    unsigned short* agg  = (unsigned short*)carve((size_t)(N0 + N1) * 128 * 2);
    unsigned short* packW = (unsigned short*)carve((size_t)22 * 16384 * 2);
    float* packb = (float*)carve((size_t)22 * 128 * 4);
    int* rowptr = (int*)carve((size_t)(N0 + 2 * N1 + 3) * 4);
    int* esrc   = (int*)carve((size_t)3 * E * 4);
    // zero-region: deg + cnt + bsums (one memset)
    char* zbase = carve(0);
    int* deg   = (int*)carve((size_t)(N0 + 2 * N1) * 4);
    int* cnt   = (int*)carve((size_t)(N0 + 2 * N1) * 4);
    int* bsums = (int*)carve(3 * 256 * 4);
    const size_t zbytes = (size_t)((char*)(bsums + 3 * 256) - zbase);

    unsigned short* hbf1 = hbf + (size_t)N0 * 128;
    unsigned short* agg0 = agg;
    unsigned short* agg1 = agg + (size_t)N0 * 128;
    const int* rp0 = rowptr;                      // dst t1 (rel0)
    const int* rp1 = rowptr + (N1 + 1);           // dst t0 (rel1)
    const int* rp2 = rowptr + (N1 + N0 + 2);      // dst t1 (rel2)
    const int* es0 = esrc;
    const int* es1 = esrc + (size_t)E;
    const int* es2 = esrc + (size_t)2 * E;

    const int eb  = (E + 255) / 256;
    const int nbx = (N0 + 1 + 511) / 512;
    const int mbN0 = (N0 + 127) / 128;
    const int mbN1 = (N1 + 127) / 128;
    const int nGemm = mbN0 + mbN1;

    // ---- d1: zero deg/cnt/bsums ----
    hipMemsetAsync(zbase, 0, zbytes, stream);

    // ---- d2: histogram + weight pack (fused) ----
    hgt_prep<<<dim3(eb, 4), 256, 0, stream>>>(
        W_in, b_in, Wk, bk, Wq, bq, Wv, bv, Wa, ba,
        a_rel, m_rel, p_rel, packW, packb,
        dst0, dst1, dst2, E, N0, N1, deg);

    // ---- d3/d4: scans ----
    hgt_scan1 <<<dim3(nbx, 3), 512, 0, stream>>>(deg, rowptr, bsums, N0, N1);
    hgt_scan23<<<dim3(nbx, 3), 512, 0, stream>>>(rowptr, bsums, N0, N1);

    // ---- d5: CSR fill + in-proj GEMM (fused) ----
    hgt_fill_inproj<<<nGemm + 3 * eb, 256, 0, stream>>>(
        src0, dst0, src1, dst1, src2, dst2, E, N0, N1,
        rowptr, cnt, (int*)esrc, eb,
        x0, x1, packW, packb, hbf, hbf1, out, nGemm, mbN0);

    for (int l = 0; l < 2; ++l) {
        const int qkv0_blk = l ? 12 : 2;
        const int qkv1_blk = l ? 15 : 5;
        const int out0_blk = l ? 20 : 10;
        const int out1_blk = l ? 21 : 11;

        // ---- merged q|kr|vr GEMM (type1 first: 5 col-blocks, heavier) ----
        mfma_gemm<0, 0, 1><<<nGemm, 256, 0, stream>>>(
            hbf1, hbf, 128, packW, packb,
            qkv1_blk, qkv0_blk, 5, 3,
            qkv1, qkv0, 640, 384,
            nullptr, nullptr, 0,
            nullptr, nullptr, nullptr,
            N1, N0, mbN1);

        // ---- merged attention (distributed-gelu epilogue; t1 blocks first) ----
        const int nb1 = (N1 + 3) / 4;
        const int nb0 = (N0 + 3) / 4;
        hgt_attn<<<nb1 + nb0, 256, 0, stream>>>(
            qkv0, qkv1, rp1, es1, rp0, es0, rp2, es2,
            agg0, agg1, N0, N1, nb1);

        // ---- merged out-proj + skip-mix ----
        mfma_gemm<0, 2, 0><<<nGemm, 256, 0, stream>>>(
            agg0, agg1, 128, packW, packb,
            out0_blk, out1_blk, 1, 1,
            hbf, hbf1, 128, 128,
            out + (size_t)(l + 1) * 128,
            out + (size_t)N0 * OLD + (size_t)(l + 1) * 128, OLD,
            hbf, hbf1, skip + l * 2, N0, N1, mbN0);
    }
}